// Round 6
// baseline (2283.428 us; speedup 1.0000x reference)
//
#include <hip/hip_runtime.h>
#include <cstdint>
#include <cstddef>

#define EPSV 1e-5f

typedef __attribute__((ext_vector_type(8))) short short8;
typedef __attribute__((ext_vector_type(4))) float f32x4;

constexpr int Bn = 64;
constexpr int Tt = 2000;
constexpr int Hh = 192;
constexpr int ROWS = 2080;   // 16 pad-lo + 2000 + 64 pad-hi
constexpr int PADLO = 16;

typedef const uint32_t __attribute__((address_space(1)))* gas_t;
typedef uint32_t __attribute__((address_space(3)))* las_t;

__device__ __forceinline__ unsigned short f2bf(float f) {
    unsigned u = __float_as_uint(f);
    u += 0x7fff + ((u >> 16) & 1);          // RNE (no NaNs in this workload)
    return (unsigned short)(u >> 16);
}
__device__ __forceinline__ float bf2f(unsigned short h) {
    return __uint_as_float(((unsigned)h) << 16);
}

// Packed hi/lo-split weights: [slot][o(64)][chunk][hi 32ci | lo 32ci] u16.
// slots: k3 -> 0..2, k5 -> 3..7, k7 -> 8..14
__device__ __align__(16) unsigned short g_p1[15 * 64 * 9 * 64];   // TCN1 (NCH=9)
__device__ __align__(16) unsigned short g_p2[15 * 64 * 6 * 64];   // TCN2 (NCH=6)
__device__ __align__(16) unsigned short g_p3[15 * 64 * 6 * 64];   // TCN3
__device__ __align__(16) unsigned short g_rp[192 * 9 * 64];       // 1x1 residual [o(192)][9][2][32]

// ---------------- weight prep: packed layout ----------------
__global__ void wprep(const float* __restrict__ w13, const float* __restrict__ w15, const float* __restrict__ w17,
                      const float* __restrict__ w23, const float* __restrict__ w25, const float* __restrict__ w27,
                      const float* __restrict__ w33, const float* __restrict__ w35, const float* __restrict__ w37,
                      const float* __restrict__ rw)
{
    const int region = blockIdx.y;
    const int i = blockIdx.x * 256 + threadIdx.x;
    if (region < 3) {
        const int CINs = (region == 0) ? 264 : 192;
        const int NCHs = (region == 0) ? 9 : 6;
        const int tot  = 15 * 64 * NCHs * 64;
        if (i >= tot) return;
        const int cil  = i & 31;
        const int hl   = (i >> 5) & 1;
        const int rest = i >> 6;
        const int c    = rest % NCHs;
        const int r2   = rest / NCHs;
        const int o    = r2 & 63;
        const int slot = r2 >> 6;
        const int ci   = c * 32 + cil;
        int br, j;
        if (slot < 3)      { br = 0; j = slot; }
        else if (slot < 8) { br = 1; j = slot - 3; }
        else               { br = 2; j = slot - 8; }
        const int Kk = 3 + 2 * br;
        const float* w;
        if (region == 0)      w = (br == 0) ? w13 : ((br == 1) ? w15 : w17);
        else if (region == 1) w = (br == 0) ? w23 : ((br == 1) ? w25 : w27);
        else                  w = (br == 0) ? w33 : ((br == 1) ? w35 : w37);
        const float v = (ci < CINs) ? w[((size_t)o * CINs + ci) * Kk + j] : 0.f;
        const unsigned short hi = f2bf(v);
        const unsigned short out = hl ? f2bf(v - bf2f(hi)) : hi;
        unsigned short* p = (region == 0) ? g_p1 : ((region == 1) ? g_p2 : g_p3);
        p[i] = out;
    } else {
        const int tot = 192 * 9 * 64;
        if (i >= tot) return;
        const int cil  = i & 31;
        const int hl   = (i >> 5) & 1;
        const int rest = i >> 6;
        const int c    = rest % 9;
        const int o    = rest / 9;
        const int ci   = c * 32 + cil;
        const float v = (ci < 264) ? rw[o * 264 + ci] : 0.f;
        const unsigned short hi = f2bf(v);
        g_rp[i] = hl ? f2bf(v - bf2f(hi)) : hi;
    }
}

// ---------------- zero the halo pad rows of a split array (unchanged) ----------------
__global__ void padzero(uint16_t* __restrict__ arr, int rowlen) {
    const int nv = rowlen >> 3;
    const int tot = Bn * 80 * nv;
    const int idx = blockIdx.x * 256 + threadIdx.x;
    if (idx >= tot) return;
    const int c8 = idx % nv;
    const int rr = idx / nv;
    const int r  = rr % 80;
    const int b  = rr / 80;
    const int row = (r < 16) ? r : (2000 + r);
    const size_t off = ((size_t)b * ROWS + row) * rowlen + (size_t)c8 * 8;
    *reinterpret_cast<uint4*>(arr + off) = make_uint4(0u, 0u, 0u, 0u);
}

// ---------------- transpose+split x (unchanged, proven) ----------------
__global__ __launch_bounds__(256) void xsplit_t(const float* __restrict__ x, uint16_t* __restrict__ xs) {
    __shared__ float lds[32][65];
    const int bid = blockIdx.x;
    const int tt = bid & 31;
    const int cc = (bid >> 5) % 9;
    const int b  = (bid >> 5) / 9;
    const int tid = threadIdx.x;
    for (int idx = tid; idx < 512; idx += 256) {
        const int r = idx >> 4, c = idx & 15;
        const int ci = cc * 32 + r;
        const int t  = tt * 64 + c * 4;
        float4 v = make_float4(0.f, 0.f, 0.f, 0.f);
        if (ci < 264) {
            const float* p = x + ((size_t)b * 264 + ci) * Tt;
            if (t + 3 < Tt) v = *reinterpret_cast<const float4*>(p + t);
            else { float* pv = &v.x; for (int i = 0; i < 4; ++i) if (t + i < Tt) pv[i] = p[t + i]; }
        }
        lds[r][c * 4 + 0] = v.x; lds[r][c * 4 + 1] = v.y;
        lds[r][c * 4 + 2] = v.z; lds[r][c * 4 + 3] = v.w;
    }
    __syncthreads();
    for (int idx = tid; idx < 2048; idx += 256) {
        const int tl = idx >> 5, cl = idx & 31;
        const int t  = tt * 64 + tl;
        if (t >= Tt) continue;
        const float v = lds[cl][tl];
        const unsigned short hi = f2bf(v);
        const unsigned short lo = f2bf(v - bf2f(hi));
        const size_t dst = ((size_t)b * ROWS + PADLO + t) * 576 + (size_t)cc * 64 + cl;
        xs[dst] = hi; xs[dst + 32] = lo;
    }
}

// ---------------- MFMA conv stage v5: union-shift + batched B-loads + TILE param ----------------
// ABL: 0 = real; 1 = no-epilogue ablation (acc sunk via asm, no global writes)
template<int STAGE, int MODE, int D, int NCH, int HALO, int RIN, int ROUT, int TILE, int ABL>
__global__ __launch_bounds__(256, 3) void conv_mfma(
    const uint16_t* __restrict__ xs,
    const float* __restrict__ b3, const float* __restrict__ b5, const float* __restrict__ b7,
    const float* __restrict__ gg, const float* __restrict__ gb,
    const float* __restrict__ gm, const float* __restrict__ gv,
    const float* __restrict__ rb,
    const float* __restrict__ sg, const float* __restrict__ sb,
    const float* __restrict__ sm, const float* __restrict__ sv,
    uint16_t* __restrict__ os, float* __restrict__ h3)
{
    constexpr int TSPAN = TILE + 2 * HALO;
    constexpr int TFN   = TILE / 32;          // t-frags per wave
    __shared__ uint16_t lds[2][TSPAN * 64];

    const int tid = threadIdx.x;
    const int wid = tid >> 6, l = tid & 63, l15 = l & 15, l4 = l >> 4;
    const int thf = wid >> 1;   // t-half
    const int par = wid & 1;    // o-half within each branch
    const int bx  = blockIdx.x;
    const int by  = blockIdx.y;
    const int t0  = bx * TILE;

    const unsigned short* wp;
    if constexpr (STAGE == 0)      wp = g_p1;
    else if constexpr (STAGE == 1) wp = g_p2;
    else                           wp = g_p3;

    const uint16_t* xb = xs + ((size_t)by * ROWS + (PADLO + t0 - HALO)) * RIN;
    const int srcslot = ((l & 7) ^ ((l >> 3) & 7)) * 8;   // inverse-swizzled source (u16)
    const int ob = par * 32 + l15;                         // o within branch, u adds 16

    f32x4 acc[3][2][TFN];
    f32x4 res[(MODE == 0) ? 3 : 1][2][(MODE == 0) ? TFN : 1];
#pragma unroll
    for (int br = 0; br < 3; ++br)
#pragma unroll
        for (int u = 0; u < 2; ++u)
#pragma unroll
            for (int tf = 0; tf < TFN; ++tf)
#pragma unroll
                for (int q = 0; q < 4; ++q) {
                    acc[br][u][tf][q] = 0.f;
                    if constexpr (MODE == 0) res[br][u][tf][q] = 0.f;
                }

#define STAGE_FN(BUF, CC)                                                                  \
    {                                                                                      \
        const uint16_t* srcb = xb + (size_t)(CC) * 64;                                     \
        for (int r0 = wid * 8; r0 < TSPAN; r0 += 32) {                                     \
            const uint16_t* src = srcb + (size_t)(r0 + (l >> 3)) * RIN + srcslot;          \
            __builtin_amdgcn_global_load_lds((gas_t)(const void*)src,                      \
                                             (las_t)(void*)&lds[BUF][r0 * 64], 16, 0, 0);  \
        }                                                                                  \
    }

#define MM(ACC, BH, BL)                                                                     \
    {                                                                                       \
        _Pragma("unroll")                                                                   \
        for (int tf = 0; tf < TFN; ++tf) {                                                  \
            ACC[tf] = __builtin_amdgcn_mfma_f32_16x16x32_bf16(Ah[tf], BH, ACC[tf], 0, 0, 0);\
            ACC[tf] = __builtin_amdgcn_mfma_f32_16x16x32_bf16(Ah[tf], BL, ACC[tf], 0, 0, 0);\
            ACC[tf] = __builtin_amdgcn_mfma_f32_16x16x32_bf16(Al[tf], BH, ACC[tf], 0, 0, 0);\
        }                                                                                   \
    }

    STAGE_FN(0, 0);
    __syncthreads();

    for (int c = 0; c < NCH; ++c) {
        const int cur = c & 1;
        if (c + 1 < NCH) STAGE_FN(cur ^ 1, c + 1);
        const char* lbc = (const char*)&lds[cur][0];
#pragma unroll
        for (int i = 0; i < 7; ++i) {
            const int s = (i - 3) * D;
            short8 Ah[TFN], Al[TFN];
#pragma unroll
            for (int tf = 0; tf < TFN; ++tf) {
                const int r  = HALO + thf * (TFN * 16) + tf * 16 + l15 + s;
                const int sw = (r & 7) << 4;
                Ah[tf] = *(const short8*)(lbc + (r * 128 + ((l4 * 16) ^ sw)));
                Al[tf] = *(const short8*)(lbc + (r * 128 + ((64 + l4 * 16) ^ sw)));
            }
#pragma unroll
            for (int u = 0; u < 2; ++u) {
                const int oo = ob + u * 16;
                // ---- batch all B-loads for this (i,u) group first (MLP), then MFMA
                short8 BH0, BL0, BH1, BL1, BH2, BL2;
                {
                    const size_t x7 = (size_t)(((8 + i) * 64 + oo) * NCH + c) * 64;
                    BH0 = *(const short8*)(wp + x7 + l4 * 8);
                    BL0 = *(const short8*)(wp + x7 + 32 + l4 * 8);
                }
                if (i >= 1 && i <= 5) {
                    const size_t x5 = (size_t)(((2 + i) * 64 + oo) * NCH + c) * 64;
                    BH1 = *(const short8*)(wp + x5 + l4 * 8);
                    BL1 = *(const short8*)(wp + x5 + 32 + l4 * 8);
                }
                if (i >= 2 && i <= 4) {
                    const size_t x3 = (size_t)(((i - 2) * 64 + oo) * NCH + c) * 64;
                    BH2 = *(const short8*)(wp + x3 + l4 * 8);
                    BL2 = *(const short8*)(wp + x3 + 32 + l4 * 8);
                }
                MM(acc[2][u], BH0, BL0)
                if (i >= 1 && i <= 5) MM(acc[1][u], BH1, BL1)
                if (i >= 2 && i <= 4) MM(acc[0][u], BH2, BL2)
            }
            if constexpr (MODE == 0) {
                if (i == 3) {   // s == 0: 1x1 conv residual, all 192 o
#pragma unroll
                    for (int u = 0; u < 2; ++u) {
                        const int oo = ob + u * 16;
#pragma unroll
                        for (int br = 0; br < 3; ++br) {
                            const size_t rx = (size_t)((br * 64 + oo) * 9 + c) * 64;
                            const short8 Rh = *(const short8*)(g_rp + rx + l4 * 8);
                            const short8 Rl = *(const short8*)(g_rp + rx + 32 + l4 * 8);
                            MM(res[br][u], Rh, Rl)
                        }
                    }
                }
            }
        }
        __syncthreads();
    }
#undef MM
#undef STAGE_FN

    if constexpr (ABL != 0) {
        // keep everything live without any global traffic (DCE guard, rule #17)
#pragma unroll
        for (int br = 0; br < 3; ++br)
#pragma unroll
            for (int u = 0; u < 2; ++u)
#pragma unroll
                for (int tf = 0; tf < TFN; ++tf)
#pragma unroll
                    for (int q = 0; q < 4; ++q)
                        asm volatile("" :: "v"(acc[br][u][tf][q]));
        return;
    }

    // ---- epilogue: BN + ReLU + residual (+ snn-BN) ; store split u16 (MODE 0/1) or fp32 (MODE 2)
#pragma unroll
    for (int br = 0; br < 3; ++br) {
        const float* bias_b = (br == 0) ? b3 : ((br == 1) ? b5 : b7);
#pragma unroll
        for (int u = 0; u < 2; ++u) {
            const int ol = par * 32 + u * 16 + l15;
            const int og = br * 64 + ol;
            const float sc = gg[og] * rsqrtf(gv[og] + EPSV);
            const float be = (bias_b[ol] - gm[og]) * sc + gb[og];
            float s2 = 0.f, b2 = 0.f, rbv = 0.f;
            if constexpr (MODE == 2) { s2 = sg[og] * rsqrtf(sv[og] + EPSV); b2 = sb[og] - sm[og] * s2; }
            if constexpr (MODE == 0) { rbv = rb[og]; }
#pragma unroll
            for (int tf = 0; tf < TFN; ++tf) {
                const int tbase = t0 + thf * (TFN * 16) + tf * 16 + l4 * 4;
                if (tbase >= Tt) continue;   // Tt%4==0: all-or-none per 4-granule
                float o4[4];
#pragma unroll
                for (int i = 0; i < 4; ++i) {
                    float v = acc[br][u][tf][i] * sc + be;
                    v = fmaxf(v, 0.f);
                    if constexpr (MODE == 0) {
                        v += res[br][u][tf][i] + rbv;
                    } else {
                        const size_t ro = ((size_t)by * ROWS + PADLO + tbase + i) * RIN
                                          + (size_t)(og >> 5) * 64 + (og & 31);
                        v += bf2f(xs[ro]) + bf2f(xs[ro + 32]);
                    }
                    if constexpr (MODE == 2) v = v * s2 + b2;
                    o4[i] = v;
                }
                if constexpr (MODE == 2) {
                    *reinterpret_cast<float4*>(h3 + ((size_t)by * Hh + og) * Tt + tbase) =
                        make_float4(o4[0], o4[1], o4[2], o4[3]);
                } else {
#pragma unroll
                    for (int i = 0; i < 4; ++i) {
                        const unsigned short hi = f2bf(o4[i]);
                        const unsigned short lo = f2bf(o4[i] - bf2f(hi));
                        const size_t dst = ((size_t)by * ROWS + PADLO + tbase + i) * ROUT
                                           + (size_t)(og >> 5) * 64 + (og & 31);
                        os[dst] = hi; os[dst + 32] = lo;
                    }
                }
            }
        }
    }
}

// ---------------- SNN + attention + classifier (unchanged, proven) ----------------
__global__ __launch_bounds__(192) void snn_head(
    const float* __restrict__ hin,
    const float* __restrict__ plif,
    const float* __restrict__ aw, const float* __restrict__ ab,
    const float* __restrict__ c1w, const float* __restrict__ c1b,
    const float* __restrict__ c1g, const float* __restrict__ c1bb,
    const float* __restrict__ c1m, const float* __restrict__ c1v,
    const float* __restrict__ c2w, const float* __restrict__ c2b,
    const float* __restrict__ c2g, const float* __restrict__ c2bb,
    const float* __restrict__ c2m, const float* __restrict__ c2v,
    const float* __restrict__ c3w, const float* __restrict__ c3b,
    float* __restrict__ outp)
{
    __shared__ uint32_t bits[192 * 65];
    __shared__ float scl[2048];
    __shared__ float red[8];
    __shared__ float pooled[192];
    __shared__ float z1[128];
    __shared__ float z2[64];

    const int tid = threadIdx.x;
    const int b   = blockIdx.x;
    const float decay = 1.f / (1.f + expf(-plif[0]));

    if (tid < 48) scl[2000 + tid] = 0.f;

    const float* row = hin + ((size_t)b * Hh + tid) * Tt;
    float v = 0.f;
    for (int c = 0; c < 62; ++c) {
        const float4* rq = reinterpret_cast<const float4*>(row + c * 32);
        float xa[32];
#pragma unroll
        for (int q = 0; q < 8; ++q) {
            float4 t4 = rq[q];
            xa[4 * q + 0] = t4.x; xa[4 * q + 1] = t4.y;
            xa[4 * q + 2] = t4.z; xa[4 * q + 3] = t4.w;
        }
        uint32_t wv = 0;
#pragma unroll
        for (int k = 0; k < 32; ++k) {
            v = fmaf(xa[k] - v, decay, v);
            if (v >= 1.f) { wv |= (1u << k); v = 0.f; }
        }
        bits[tid * 65 + c] = wv;
    }
    {
        const float4* rq = reinterpret_cast<const float4*>(row + 62 * 32);
        float xa[16];
#pragma unroll
        for (int q = 0; q < 4; ++q) {
            float4 t4 = rq[q];
            xa[4 * q + 0] = t4.x; xa[4 * q + 1] = t4.y;
            xa[4 * q + 2] = t4.z; xa[4 * q + 3] = t4.w;
        }
        uint32_t wv = 0;
#pragma unroll
        for (int k = 0; k < 16; ++k) {
            v = fmaf(xa[k] - v, decay, v);
            if (v >= 1.f) { wv |= (1u << k); v = 0.f; }
        }
        bits[tid * 65 + 62] = wv;
    }
    __syncthreads();

    const float tanh1 = 0.7615941559557649f;
    const float abv   = ab[0];
    for (int t = tid; t < Tt; t += 192) {
        const int wd = t >> 5, bp = t & 31;
        float s = 0.f;
#pragma unroll 8
        for (int hh = 0; hh < 192; ++hh)
            s += ((bits[hh * 65 + wd] >> bp) & 1u) ? aw[hh] : 0.f;
        scl[t] = s * tanh1 + abv;
    }
    __syncthreads();

    float lm = -1e30f;
    for (int t = tid; t < Tt; t += 192) lm = fmaxf(lm, scl[t]);
#pragma unroll
    for (int off = 32; off > 0; off >>= 1) lm = fmaxf(lm, __shfl_xor(lm, off));
    if ((tid & 63) == 0) red[tid >> 6] = lm;
    __syncthreads();
    const float m = fmaxf(red[0], fmaxf(red[1], red[2]));
    float ls = 0.f;
    for (int t = tid; t < Tt; t += 192) {
        float e = expf(scl[t] - m);
        scl[t] = e;
        ls += e;
    }
#pragma unroll
    for (int off = 32; off > 0; off >>= 1) ls += __shfl_xor(ls, off);
    if ((tid & 63) == 0) red[4 + (tid >> 6)] = ls;
    __syncthreads();
    const float inv = 1.f / (red[4] + red[5] + red[6]);

    float p = 0.f;
    for (int wd = 0; wd < 63; ++wd) {
        uint32_t bw = bits[tid * 65 + wd];
        if (bw) {
#pragma unroll
            for (int k = 0; k < 32; ++k)
                if ((bw >> k) & 1u) p += scl[wd * 32 + k];
        }
    }
    pooled[tid] = p * inv;
    __syncthreads();

    if (tid < 128) {
        const float4* wr = reinterpret_cast<const float4*>(c1w + (size_t)tid * 192);
        const float4* pr = reinterpret_cast<const float4*>(pooled);
        float s = 0.f;
#pragma unroll 8
        for (int q = 0; q < 48; ++q) {
            float4 wv4 = wr[q]; float4 pv4 = pr[q];
            s += wv4.x * pv4.x + wv4.y * pv4.y + wv4.z * pv4.z + wv4.w * pv4.w;
        }
        s += c1b[tid];
        s = (s - c1m[tid]) * (c1g[tid] / sqrtf(c1v[tid] + EPSV)) + c1bb[tid];
        s = s * 0.5f * (1.f + erff(s * 0.70710678118654752f));
        z1[tid] = s;
    }
    __syncthreads();
    if (tid < 64) {
        const float4* wr = reinterpret_cast<const float4*>(c2w + (size_t)tid * 128);
        const float4* zr = reinterpret_cast<const float4*>(z1);
        float s = 0.f;
#pragma unroll 8
        for (int q = 0; q < 32; ++q) {
            float4 wv4 = wr[q]; float4 zv4 = zr[q];
            s += wv4.x * zv4.x + wv4.y * zv4.y + wv4.z * zv4.z + wv4.w * zv4.w;
        }
        s += c2b[tid];
        s = (s - c2m[tid]) * (c2g[tid] / sqrtf(c2v[tid] + EPSV)) + c2bb[tid];
        s = s * 0.5f * (1.f + erff(s * 0.70710678118654752f));
        z2[tid] = s;
    }
    __syncthreads();
    if (tid < 4) {
        float s = c3b[tid];
#pragma unroll 8
        for (int hh = 0; hh < 64; ++hh) s += z2[hh] * c3w[tid * 64 + hh];
        outp[b * 4 + tid] = s;
    }
}

extern "C" void kernel_launch(void* const* d_in, const int* in_sizes, int n_in,
                              void* d_out, int out_size, void* d_ws, size_t ws_size,
                              hipStream_t stream) {
    (void)in_sizes; (void)n_in; (void)out_size; (void)ws_size;
    const float* x     = (const float*)d_in[0];
    const float* t1_w3 = (const float*)d_in[1];
    const float* t1_b3 = (const float*)d_in[2];
    const float* t1_w5 = (const float*)d_in[3];
    const float* t1_b5 = (const float*)d_in[4];
    const float* t1_w7 = (const float*)d_in[5];
    const float* t1_b7 = (const float*)d_in[6];
    const float* t1_g  = (const float*)d_in[7];
    const float* t1_bb = (const float*)d_in[8];
    const float* t1_m  = (const float*)d_in[9];
    const float* t1_v  = (const float*)d_in[10];
    const float* t2_w3 = (const float*)d_in[11];
    const float* t2_b3 = (const float*)d_in[12];
    const float* t2_w5 = (const float*)d_in[13];
    const float* t2_b5 = (const float*)d_in[14];
    const float* t2_w7 = (const float*)d_in[15];
    const float* t2_b7 = (const float*)d_in[16];
    const float* t2_g  = (const float*)d_in[17];
    const float* t2_bb = (const float*)d_in[18];
    const float* t2_m  = (const float*)d_in[19];
    const float* t2_v  = (const float*)d_in[20];
    const float* t3_w3 = (const float*)d_in[21];
    const float* t3_b3 = (const float*)d_in[22];
    const float* t3_w5 = (const float*)d_in[23];
    const float* t3_b5 = (const float*)d_in[24];
    const float* t3_w7 = (const float*)d_in[25];
    const float* t3_b7 = (const float*)d_in[26];
    const float* t3_g  = (const float*)d_in[27];
    const float* t3_bb = (const float*)d_in[28];
    const float* t3_m  = (const float*)d_in[29];
    const float* t3_v  = (const float*)d_in[30];
    const float* t1_rw = (const float*)d_in[31];
    const float* t1_rb = (const float*)d_in[32];
    const float* snn_g = (const float*)d_in[33];
    const float* snn_bb= (const float*)d_in[34];
    const float* snn_m = (const float*)d_in[35];
    const float* snn_v = (const float*)d_in[36];
    const float* plifw = (const float*)d_in[37];
    const float* attnw = (const float*)d_in[38];
    const float* attnb = (const float*)d_in[39];
    const float* c1_w  = (const float*)d_in[40];
    const float* c1_b  = (const float*)d_in[41];
    const float* c1_g  = (const float*)d_in[42];
    const float* c1_bb = (const float*)d_in[43];
    const float* c1_m  = (const float*)d_in[44];
    const float* c1_v  = (const float*)d_in[45];
    const float* c2_w  = (const float*)d_in[46];
    const float* c2_b  = (const float*)d_in[47];
    const float* c2_g  = (const float*)d_in[48];
    const float* c2_bb = (const float*)d_in[49];
    const float* c2_m  = (const float*)d_in[50];
    const float* c2_v  = (const float*)d_in[51];
    const float* c3_w  = (const float*)d_in[52];
    const float* c3_b  = (const float*)d_in[53];

    float* out = (float*)d_out;

    // ws layout (aliased, sequential lifetimes):
    //   x1s [64][2080][576] u16 @ 0            -- dead after TCN1
    //   h1s [64][2080][384] u16 @ 153,354,240  -- dead after TCN2 (then reused as h3)
    //   h2s @ 0 (reuses x1s; stays intact -> ablation input)
    uint16_t* x1s = (uint16_t*)d_ws;
    uint16_t* h1s = x1s + (size_t)76677120;
    uint16_t* h2s = x1s;
    float*    h3  = (float*)((char*)d_ws + (size_t)153354240);

    wprep<<<dim3(2160, 4), dim3(256), 0, stream>>>(
        t1_w3, t1_w5, t1_w7, t2_w3, t2_w5, t2_w7, t3_w3, t3_w5, t3_w7, t1_rw);

    padzero<<<1440, 256, 0, stream>>>(x1s, 576);
    padzero<<<960,  256, 0, stream>>>(h1s, 384);

    xsplit_t<<<64 * 9 * 32, 256, 0, stream>>>(x, x1s);

    // ---- TCN1: x1s -> h1s (d=1, conv residual), TILE=64
    conv_mfma<0, 0, 1, 9, 4, 576, 384, 64, 0><<<dim3(32, 64), 256, 0, stream>>>(
        x1s, t1_b3, t1_b5, t1_b7, t1_g, t1_bb, t1_m, t1_v,
        t1_rb, nullptr, nullptr, nullptr, nullptr, h1s, nullptr);

    padzero<<<960, 256, 0, stream>>>(h2s, 384);   // x1s dead; carve h2s pads

    // ---- TCN2: h1s -> h2s (d=2, identity residual), TILE=128
    conv_mfma<1, 1, 2, 6, 8, 384, 384, 128, 0><<<dim3(16, 64), 256, 0, stream>>>(
        h1s, t2_b3, t2_b5, t2_b7, t2_g, t2_bb, t2_m, t2_v,
        nullptr, nullptr, nullptr, nullptr, nullptr, h2s, nullptr);

    // ---- TCN3: h2s -> h3 fp32 (d=4, identity residual + snn-BN fold), TILE=128
    conv_mfma<2, 2, 4, 6, 12, 384, 384, 128, 0><<<dim3(16, 64), 256, 0, stream>>>(
        h2s, t3_b3, t3_b5, t3_b7, t3_g, t3_bb, t3_m, t3_v,
        nullptr, snn_g, snn_bb, snn_m, snn_v, nullptr, h3);

    // ---- SNN scan + attention pooling + classifier
    snn_head<<<dim3(Bn), dim3(192), 0, stream>>>(h3, plifw, attnw, attnb,
        c1_w, c1_b, c1_g, c1_bb, c1_m, c1_v,
        c2_w, c2_b, c2_g, c2_bb, c2_m, c2_v, c3_w, c3_b, out);

    // ---- ABLATION (diagnostic, writes nothing): TCN2 config minus epilogue.
    // Reads h2s (defined: written by TCN2 this call). Compare its per-dispatch
    // counters vs the real TCN2 dispatch to attribute epilogue vs chunk-loop cost.
    conv_mfma<1, 1, 2, 6, 8, 384, 384, 128, 1><<<dim3(16, 64), 256, 0, stream>>>(
        h2s, t2_b3, t2_b5, t2_b7, t2_g, t2_bb, t2_m, t2_v,
        nullptr, nullptr, nullptr, nullptr, nullptr, nullptr, nullptr);
}

// Round 8
// 1246.264 us; speedup vs baseline: 1.8322x; 1.8322x over previous
//
#include <hip/hip_runtime.h>
#include <cstdint>
#include <cstddef>

#define EPSV 1e-5f

typedef __attribute__((ext_vector_type(8))) short short8;
typedef __attribute__((ext_vector_type(4))) float f32x4;

constexpr int Bn = 64;
constexpr int Tt = 2000;
constexpr int Hh = 192;
constexpr int ROWS = 2080;   // 16 pad-lo + 2000 + 64 pad-hi
constexpr int PADLO = 16;

typedef const uint32_t __attribute__((address_space(1)))* gas_t;
typedef uint32_t __attribute__((address_space(3)))* las_t;

__device__ __forceinline__ unsigned short f2bf(float f) {
    unsigned u = __float_as_uint(f);
    u += 0x7fff + ((u >> 16) & 1);          // RNE (no NaNs in this workload)
    return (unsigned short)(u >> 16);
}
__device__ __forceinline__ float bf2f(unsigned short h) {
    return __uint_as_float(((unsigned)h) << 16);
}

// Packed hi/lo-split weights: [slot][o(64)][chunk][hi 32ci | lo 32ci] u16.
// slots: k3 -> 0..2, k5 -> 3..7, k7 -> 8..14
__device__ __align__(16) unsigned short g_p1[15 * 64 * 9 * 64];   // TCN1 (NCH=9)
__device__ __align__(16) unsigned short g_p2[15 * 64 * 6 * 64];   // TCN2 (NCH=6)
__device__ __align__(16) unsigned short g_p3[15 * 64 * 6 * 64];   // TCN3
__device__ __align__(16) unsigned short g_rp[192 * 9 * 64];       // 1x1 residual [o(192)][9][2][32]

// ---------------- weight prep: packed layout (unchanged, proven) ----------------
__global__ void wprep(const float* __restrict__ w13, const float* __restrict__ w15, const float* __restrict__ w17,
                      const float* __restrict__ w23, const float* __restrict__ w25, const float* __restrict__ w27,
                      const float* __restrict__ w33, const float* __restrict__ w35, const float* __restrict__ w37,
                      const float* __restrict__ rw)
{
    const int region = blockIdx.y;
    const int i = blockIdx.x * 256 + threadIdx.x;
    if (region < 3) {
        const int CINs = (region == 0) ? 264 : 192;
        const int NCHs = (region == 0) ? 9 : 6;
        const int tot  = 15 * 64 * NCHs * 64;
        if (i >= tot) return;
        const int cil  = i & 31;
        const int hl   = (i >> 5) & 1;
        const int rest = i >> 6;
        const int c    = rest % NCHs;
        const int r2   = rest / NCHs;
        const int o    = r2 & 63;
        const int slot = r2 >> 6;
        const int ci   = c * 32 + cil;
        int br, j;
        if (slot < 3)      { br = 0; j = slot; }
        else if (slot < 8) { br = 1; j = slot - 3; }
        else               { br = 2; j = slot - 8; }
        const int Kk = 3 + 2 * br;
        const float* w;
        if (region == 0)      w = (br == 0) ? w13 : ((br == 1) ? w15 : w17);
        else if (region == 1) w = (br == 0) ? w23 : ((br == 1) ? w25 : w27);
        else                  w = (br == 0) ? w33 : ((br == 1) ? w35 : w37);
        const float v = (ci < CINs) ? w[((size_t)o * CINs + ci) * Kk + j] : 0.f;
        const unsigned short hi = f2bf(v);
        const unsigned short out = hl ? f2bf(v - bf2f(hi)) : hi;
        unsigned short* p = (region == 0) ? g_p1 : ((region == 1) ? g_p2 : g_p3);
        p[i] = out;
    } else {
        const int tot = 192 * 9 * 64;
        if (i >= tot) return;
        const int cil  = i & 31;
        const int hl   = (i >> 5) & 1;
        const int rest = i >> 6;
        const int c    = rest % 9;
        const int o    = rest / 9;
        const int ci   = c * 32 + cil;
        const float v = (ci < 264) ? rw[o * 264 + ci] : 0.f;
        const unsigned short hi = f2bf(v);
        g_rp[i] = hl ? f2bf(v - bf2f(hi)) : hi;
    }
}

// ---------------- zero the halo pad rows of a split array (unchanged) ----------------
__global__ void padzero(uint16_t* __restrict__ arr, int rowlen) {
    const int nv = rowlen >> 3;
    const int tot = Bn * 80 * nv;
    const int idx = blockIdx.x * 256 + threadIdx.x;
    if (idx >= tot) return;
    const int c8 = idx % nv;
    const int rr = idx / nv;
    const int r  = rr % 80;
    const int b  = rr / 80;
    const int row = (r < 16) ? r : (2000 + r);
    const size_t off = ((size_t)b * ROWS + row) * rowlen + (size_t)c8 * 8;
    *reinterpret_cast<uint4*>(arr + off) = make_uint4(0u, 0u, 0u, 0u);
}

// ---------------- transpose+split x (unchanged, proven) ----------------
__global__ __launch_bounds__(256) void xsplit_t(const float* __restrict__ x, uint16_t* __restrict__ xs) {
    __shared__ float lds[32][65];
    const int bid = blockIdx.x;
    const int tt = bid & 31;
    const int cc = (bid >> 5) % 9;
    const int b  = (bid >> 5) / 9;
    const int tid = threadIdx.x;
    for (int idx = tid; idx < 512; idx += 256) {
        const int r = idx >> 4, c = idx & 15;
        const int ci = cc * 32 + r;
        const int t  = tt * 64 + c * 4;
        float4 v = make_float4(0.f, 0.f, 0.f, 0.f);
        if (ci < 264) {
            const float* p = x + ((size_t)b * 264 + ci) * Tt;
            if (t + 3 < Tt) v = *reinterpret_cast<const float4*>(p + t);
            else { float* pv = &v.x; for (int i = 0; i < 4; ++i) if (t + i < Tt) pv[i] = p[t + i]; }
        }
        lds[r][c * 4 + 0] = v.x; lds[r][c * 4 + 1] = v.y;
        lds[r][c * 4 + 2] = v.z; lds[r][c * 4 + 3] = v.w;
    }
    __syncthreads();
    for (int idx = tid; idx < 2048; idx += 256) {
        const int tl = idx >> 5, cl = idx & 31;
        const int t  = tt * 64 + tl;
        if (t >= Tt) continue;
        const float v = lds[cl][tl];
        const unsigned short hi = f2bf(v);
        const unsigned short lo = f2bf(v - bf2f(hi));
        const size_t dst = ((size_t)b * ROWS + PADLO + t) * 576 + (size_t)cc * 64 + cl;
        xs[dst] = hi; xs[dst + 32] = lo;
    }
}

// ---------------- MFMA conv v6: 8-wave blocks, big TILE, branch-balanced frags ----------------
// 512 thr = 8 waves = 2 t-halves x 4 o-quarters. Wave owns one 16-o frag per branch:
// frag f in {0,1,2} -> branch k(3+2f), o = f*64 + oq*16 + l15. Weight traffic amortized
// over TILE t (the round-6 limiter: per-chunk L2 weight restream saturated L2 BW).
template<int STAGE, int MODE, int D, int NCH, int HALO, int RIN, int ROUT, int TILE>
__global__ __launch_bounds__(512, 2) void conv_mfma(
    const uint16_t* __restrict__ xs,
    const float* __restrict__ b3, const float* __restrict__ b5, const float* __restrict__ b7,
    const float* __restrict__ gg, const float* __restrict__ gb,
    const float* __restrict__ gm, const float* __restrict__ gv,
    const float* __restrict__ rb,
    const float* __restrict__ sg, const float* __restrict__ sb,
    const float* __restrict__ sm, const float* __restrict__ sv,
    uint16_t* __restrict__ os, float* __restrict__ h3)
{
    constexpr int TSPAN = TILE + 2 * HALO;
    constexpr int TFN   = TILE / 32;          // t-frags per wave (per t-half)
    __shared__ uint16_t lds[2][TSPAN * 64];

    const int tid = threadIdx.x;
    const int wid = tid >> 6, l = tid & 63, l15 = l & 15, l4 = l >> 4;
    const int th  = wid >> 2;   // t-half
    const int oq  = wid & 3;    // o-quarter (one 16-o frag per branch)
    const int bx  = blockIdx.x;
    const int by  = blockIdx.y;
    const int t0  = bx * TILE;

    const unsigned short* wp;
    if constexpr (STAGE == 0)      wp = g_p1;
    else if constexpr (STAGE == 1) wp = g_p2;
    else                           wp = g_p3;

    const uint16_t* xb = xs + ((size_t)by * ROWS + (PADLO + t0 - HALO)) * RIN;
    const int srcslot = ((l & 7) ^ ((l >> 3) & 7)) * 8;   // inverse-swizzled source (u16)
    const int ol = oq * 16 + l15;                          // o within branch

    f32x4 acc[3][TFN];
    f32x4 res[(MODE == 0) ? 3 : 1][(MODE == 0) ? TFN : 1];
#pragma unroll
    for (int f = 0; f < 3; ++f)
#pragma unroll
        for (int tf = 0; tf < TFN; ++tf)
#pragma unroll
            for (int q = 0; q < 4; ++q) {
                acc[f][tf][q] = 0.f;
                if constexpr (MODE == 0) res[f][tf][q] = 0.f;
            }

#define STAGE_FN(BUF, CC)                                                                  \
    {                                                                                      \
        const uint16_t* srcb = xb + (size_t)(CC) * 64;                                     \
        for (int r0 = wid * 8; r0 < TSPAN; r0 += 64) {                                     \
            const uint16_t* src = srcb + (size_t)(r0 + (l >> 3)) * RIN + srcslot;          \
            __builtin_amdgcn_global_load_lds((gas_t)(const void*)src,                      \
                                             (las_t)(void*)&lds[BUF][r0 * 64], 16, 0, 0);  \
        }                                                                                  \
    }

    STAGE_FN(0, 0);
    __syncthreads();

    for (int c = 0; c < NCH; ++c) {
        const int cur = c & 1;
        if (c + 1 < NCH) STAGE_FN(cur ^ 1, c + 1);
        const char* lbc = (const char*)&lds[cur][0];
#pragma unroll
        for (int i = 0; i < 7; ++i) {
            const int s = (i - 3) * D;
            const bool has5 = (i >= 1 && i <= 5);
            const bool has3 = (i >= 2 && i <= 4);
            // ---- batch this shift's B-loads (<=6), then stream tf with 2 ds_reads + 9 MFMAs
            short8 B7h, B7l, B5h, B5l, B3h, B3l;
            short8 R0h, R0l, R1h, R1l, R2h, R2l;
            {
                const size_t x7 = (size_t)(((8 + i) * 64 + ol) * NCH + c) * 64 + l4 * 8;
                B7h = *(const short8*)(wp + x7);
                B7l = *(const short8*)(wp + x7 + 32);
            }
            if (has5) {
                const size_t x5 = (size_t)(((2 + i) * 64 + ol) * NCH + c) * 64 + l4 * 8;
                B5h = *(const short8*)(wp + x5);
                B5l = *(const short8*)(wp + x5 + 32);
            }
            if (has3) {
                const size_t x3 = (size_t)(((i - 2) * 64 + ol) * NCH + c) * 64 + l4 * 8;
                B3h = *(const short8*)(wp + x3);
                B3l = *(const short8*)(wp + x3 + 32);
            }
            if constexpr (MODE == 0) {
                if (i == 3) {
                    const size_t r0x = (size_t)((0 * 64 + ol) * 9 + c) * 64 + l4 * 8;
                    const size_t r1x = (size_t)((1 * 64 + ol) * 9 + c) * 64 + l4 * 8;
                    const size_t r2x = (size_t)((2 * 64 + ol) * 9 + c) * 64 + l4 * 8;
                    R0h = *(const short8*)(g_rp + r0x); R0l = *(const short8*)(g_rp + r0x + 32);
                    R1h = *(const short8*)(g_rp + r1x); R1l = *(const short8*)(g_rp + r1x + 32);
                    R2h = *(const short8*)(g_rp + r2x); R2l = *(const short8*)(g_rp + r2x + 32);
                }
            }
#pragma unroll
            for (int tf = 0; tf < TFN; ++tf) {
                const int r  = HALO + th * (TFN * 16) + tf * 16 + l15 + s;
                const int sw = (r & 7) << 4;
                const short8 Ah = *(const short8*)(lbc + (r * 128 + ((l4 * 16) ^ sw)));
                const short8 Al = *(const short8*)(lbc + (r * 128 + ((64 + l4 * 16) ^ sw)));
#define MM3(ACC, BH, BL)                                                                    \
                ACC = __builtin_amdgcn_mfma_f32_16x16x32_bf16(Ah, BH, ACC, 0, 0, 0);        \
                ACC = __builtin_amdgcn_mfma_f32_16x16x32_bf16(Ah, BL, ACC, 0, 0, 0);        \
                ACC = __builtin_amdgcn_mfma_f32_16x16x32_bf16(Al, BH, ACC, 0, 0, 0);
                MM3(acc[2][tf], B7h, B7l)
                if (has5) { MM3(acc[1][tf], B5h, B5l) }
                if (has3) { MM3(acc[0][tf], B3h, B3l) }
                if constexpr (MODE == 0) {
                    if (i == 3) {
                        MM3(res[0][tf], R0h, R0l)
                        MM3(res[1][tf], R1h, R1l)
                        MM3(res[2][tf], R2h, R2l)
                    }
                }
#undef MM3
            }
        }
        __syncthreads();
    }
#undef STAGE_FN

    // ---- epilogue: BN + ReLU + residual (+ snn-BN) ; store split u16 (MODE 0/1) or fp32 (MODE 2)
#pragma unroll
    for (int f = 0; f < 3; ++f) {
        const float* bias_b = (f == 0) ? b3 : ((f == 1) ? b5 : b7);
        const int og = f * 64 + ol;
        const float sc = gg[og] * rsqrtf(gv[og] + EPSV);
        const float be = (bias_b[ol] - gm[og]) * sc + gb[og];
        float s2 = 0.f, b2 = 0.f, rbv = 0.f;
        if constexpr (MODE == 2) { s2 = sg[og] * rsqrtf(sv[og] + EPSV); b2 = sb[og] - sm[og] * s2; }
        if constexpr (MODE == 0) { rbv = rb[og]; }
#pragma unroll
        for (int tf = 0; tf < TFN; ++tf) {
            const int tbase = t0 + th * (TFN * 16) + tf * 16 + l4 * 4;
            if (tbase >= Tt) continue;   // Tt%4==0: all-or-none per 4-granule
            float o4[4];
#pragma unroll
            for (int i = 0; i < 4; ++i) {
                float v = acc[f][tf][i] * sc + be;
                v = fmaxf(v, 0.f);
                if constexpr (MODE == 0) {
                    v += res[f][tf][i] + rbv;
                } else {
                    const size_t ro = ((size_t)by * ROWS + PADLO + tbase + i) * RIN
                                      + (size_t)(og >> 5) * 64 + (og & 31);
                    v += bf2f(xs[ro]) + bf2f(xs[ro + 32]);
                }
                if constexpr (MODE == 2) v = v * s2 + b2;
                o4[i] = v;
            }
            if constexpr (MODE == 2) {
                *reinterpret_cast<float4*>(h3 + ((size_t)by * Hh + og) * Tt + tbase) =
                    make_float4(o4[0], o4[1], o4[2], o4[3]);
            } else {
#pragma unroll
                for (int i = 0; i < 4; ++i) {
                    const unsigned short hi = f2bf(o4[i]);
                    const unsigned short lo = f2bf(o4[i] - bf2f(hi));
                    const size_t dst = ((size_t)by * ROWS + PADLO + tbase + i) * ROUT
                                       + (size_t)(og >> 5) * 64 + (og & 31);
                    os[dst] = hi; os[dst + 32] = lo;
                }
            }
        }
    }
}

// ---------------- SNN + attention + classifier (unchanged, proven) ----------------
__global__ __launch_bounds__(192) void snn_head(
    const float* __restrict__ hin,
    const float* __restrict__ plif,
    const float* __restrict__ aw, const float* __restrict__ ab,
    const float* __restrict__ c1w, const float* __restrict__ c1b,
    const float* __restrict__ c1g, const float* __restrict__ c1bb,
    const float* __restrict__ c1m, const float* __restrict__ c1v,
    const float* __restrict__ c2w, const float* __restrict__ c2b,
    const float* __restrict__ c2g, const float* __restrict__ c2bb,
    const float* __restrict__ c2m, const float* __restrict__ c2v,
    const float* __restrict__ c3w, const float* __restrict__ c3b,
    float* __restrict__ outp)
{
    __shared__ uint32_t bits[192 * 65];
    __shared__ float scl[2048];
    __shared__ float red[8];
    __shared__ float pooled[192];
    __shared__ float z1[128];
    __shared__ float z2[64];

    const int tid = threadIdx.x;
    const int b   = blockIdx.x;
    const float decay = 1.f / (1.f + expf(-plif[0]));

    if (tid < 48) scl[2000 + tid] = 0.f;

    const float* row = hin + ((size_t)b * Hh + tid) * Tt;
    float v = 0.f;
    for (int c = 0; c < 62; ++c) {
        const float4* rq = reinterpret_cast<const float4*>(row + c * 32);
        float xa[32];
#pragma unroll
        for (int q = 0; q < 8; ++q) {
            float4 t4 = rq[q];
            xa[4 * q + 0] = t4.x; xa[4 * q + 1] = t4.y;
            xa[4 * q + 2] = t4.z; xa[4 * q + 3] = t4.w;
        }
        uint32_t wv = 0;
#pragma unroll
        for (int k = 0; k < 32; ++k) {
            v = fmaf(xa[k] - v, decay, v);
            if (v >= 1.f) { wv |= (1u << k); v = 0.f; }
        }
        bits[tid * 65 + c] = wv;
    }
    {
        const float4* rq = reinterpret_cast<const float4*>(row + 62 * 32);
        float xa[16];
#pragma unroll
        for (int q = 0; q < 4; ++q) {
            float4 t4 = rq[q];
            xa[4 * q + 0] = t4.x; xa[4 * q + 1] = t4.y;
            xa[4 * q + 2] = t4.z; xa[4 * q + 3] = t4.w;
        }
        uint32_t wv = 0;
#pragma unroll
        for (int k = 0; k < 16; ++k) {
            v = fmaf(xa[k] - v, decay, v);
            if (v >= 1.f) { wv |= (1u << k); v = 0.f; }
        }
        bits[tid * 65 + 62] = wv;
    }
    __syncthreads();

    const float tanh1 = 0.7615941559557649f;
    const float abv   = ab[0];
    for (int t = tid; t < Tt; t += 192) {
        const int wd = t >> 5, bp = t & 31;
        float s = 0.f;
#pragma unroll 8
        for (int hh = 0; hh < 192; ++hh)
            s += ((bits[hh * 65 + wd] >> bp) & 1u) ? aw[hh] : 0.f;
        scl[t] = s * tanh1 + abv;
    }
    __syncthreads();

    float lm = -1e30f;
    for (int t = tid; t < Tt; t += 192) lm = fmaxf(lm, scl[t]);
#pragma unroll
    for (int off = 32; off > 0; off >>= 1) lm = fmaxf(lm, __shfl_xor(lm, off));
    if ((tid & 63) == 0) red[tid >> 6] = lm;
    __syncthreads();
    const float m = fmaxf(red[0], fmaxf(red[1], red[2]));
    float ls = 0.f;
    for (int t = tid; t < Tt; t += 192) {
        float e = expf(scl[t] - m);
        scl[t] = e;
        ls += e;
    }
#pragma unroll
    for (int off = 32; off > 0; off >>= 1) ls += __shfl_xor(ls, off);
    if ((tid & 63) == 0) red[4 + (tid >> 6)] = ls;
    __syncthreads();
    const float inv = 1.f / (red[4] + red[5] + red[6]);

    float p = 0.f;
    for (int wd = 0; wd < 63; ++wd) {
        uint32_t bw = bits[tid * 65 + wd];
        if (bw) {
#pragma unroll
            for (int k = 0; k < 32; ++k)
                if ((bw >> k) & 1u) p += scl[wd * 32 + k];
        }
    }
    pooled[tid] = p * inv;
    __syncthreads();

    if (tid < 128) {
        const float4* wr = reinterpret_cast<const float4*>(c1w + (size_t)tid * 192);
        const float4* pr = reinterpret_cast<const float4*>(pooled);
        float s = 0.f;
#pragma unroll 8
        for (int q = 0; q < 48; ++q) {
            float4 wv4 = wr[q]; float4 pv4 = pr[q];
            s += wv4.x * pv4.x + wv4.y * pv4.y + wv4.z * pv4.z + wv4.w * pv4.w;
        }
        s += c1b[tid];
        s = (s - c1m[tid]) * (c1g[tid] / sqrtf(c1v[tid] + EPSV)) + c1bb[tid];
        s = s * 0.5f * (1.f + erff(s * 0.70710678118654752f));
        z1[tid] = s;
    }
    __syncthreads();
    if (tid < 64) {
        const float4* wr = reinterpret_cast<const float4*>(c2w + (size_t)tid * 128);
        const float4* zr = reinterpret_cast<const float4*>(z1);
        float s = 0.f;
#pragma unroll 8
        for (int q = 0; q < 32; ++q) {
            float4 wv4 = wr[q]; float4 zv4 = zr[q];
            s += wv4.x * zv4.x + wv4.y * zv4.y + wv4.z * zv4.z + wv4.w * zv4.w;
        }
        s += c2b[tid];
        s = (s - c2m[tid]) * (c2g[tid] / sqrtf(c2v[tid] + EPSV)) + c2bb[tid];
        s = s * 0.5f * (1.f + erff(s * 0.70710678118654752f));
        z2[tid] = s;
    }
    __syncthreads();
    if (tid < 4) {
        float s = c3b[tid];
#pragma unroll 8
        for (int hh = 0; hh < 64; ++hh) s += z2[hh] * c3w[tid * 64 + hh];
        outp[b * 4 + tid] = s;
    }
}

extern "C" void kernel_launch(void* const* d_in, const int* in_sizes, int n_in,
                              void* d_out, int out_size, void* d_ws, size_t ws_size,
                              hipStream_t stream) {
    (void)in_sizes; (void)n_in; (void)out_size; (void)ws_size;
    const float* x     = (const float*)d_in[0];
    const float* t1_w3 = (const float*)d_in[1];
    const float* t1_b3 = (const float*)d_in[2];
    const float* t1_w5 = (const float*)d_in[3];
    const float* t1_b5 = (const float*)d_in[4];
    const float* t1_w7 = (const float*)d_in[5];
    const float* t1_b7 = (const float*)d_in[6];
    const float* t1_g  = (const float*)d_in[7];
    const float* t1_bb = (const float*)d_in[8];
    const float* t1_m  = (const float*)d_in[9];
    const float* t1_v  = (const float*)d_in[10];
    const float* t2_w3 = (const float*)d_in[11];
    const float* t2_b3 = (const float*)d_in[12];
    const float* t2_w5 = (const float*)d_in[13];
    const float* t2_b5 = (const float*)d_in[14];
    const float* t2_w7 = (const float*)d_in[15];
    const float* t2_b7 = (const float*)d_in[16];
    const float* t2_g  = (const float*)d_in[17];
    const float* t2_bb = (const float*)d_in[18];
    const float* t2_m  = (const float*)d_in[19];
    const float* t2_v  = (const float*)d_in[20];
    const float* t3_w3 = (const float*)d_in[21];
    const float* t3_b3 = (const float*)d_in[22];
    const float* t3_w5 = (const float*)d_in[23];
    const float* t3_b5 = (const float*)d_in[24];
    const float* t3_w7 = (const float*)d_in[25];
    const float* t3_b7 = (const float*)d_in[26];
    const float* t3_g  = (const float*)d_in[27];
    const float* t3_bb = (const float*)d_in[28];
    const float* t3_m  = (const float*)d_in[29];
    const float* t3_v  = (const float*)d_in[30];
    const float* t1_rw = (const float*)d_in[31];
    const float* t1_rb = (const float*)d_in[32];
    const float* snn_g = (const float*)d_in[33];
    const float* snn_bb= (const float*)d_in[34];
    const float* snn_m = (const float*)d_in[35];
    const float* snn_v = (const float*)d_in[36];
    const float* plifw = (const float*)d_in[37];
    const float* attnw = (const float*)d_in[38];
    const float* attnb = (const float*)d_in[39];
    const float* c1_w  = (const float*)d_in[40];
    const float* c1_b  = (const float*)d_in[41];
    const float* c1_g  = (const float*)d_in[42];
    const float* c1_bb = (const float*)d_in[43];
    const float* c1_m  = (const float*)d_in[44];
    const float* c1_v  = (const float*)d_in[45];
    const float* c2_w  = (const float*)d_in[46];
    const float* c2_b  = (const float*)d_in[47];
    const float* c2_g  = (const float*)d_in[48];
    const float* c2_bb = (const float*)d_in[49];
    const float* c2_m  = (const float*)d_in[50];
    const float* c2_v  = (const float*)d_in[51];
    const float* c3_w  = (const float*)d_in[52];
    const float* c3_b  = (const float*)d_in[53];

    float* out = (float*)d_out;

    // ws layout (aliased, sequential lifetimes):
    //   x1s [64][2080][576] u16 @ 0            -- dead after TCN1
    //   h1s [64][2080][384] u16 @ 153,354,240  -- dead after TCN2 (then reused as h3)
    //   h2s @ 0 (reuses x1s)
    uint16_t* x1s = (uint16_t*)d_ws;
    uint16_t* h1s = x1s + (size_t)76677120;
    uint16_t* h2s = x1s;
    float*    h3  = (float*)((char*)d_ws + (size_t)153354240);

    wprep<<<dim3(2160, 4), dim3(256), 0, stream>>>(
        t1_w3, t1_w5, t1_w7, t2_w3, t2_w5, t2_w7, t3_w3, t3_w5, t3_w7, t1_rw);

    padzero<<<1440, 256, 0, stream>>>(x1s, 576);
    padzero<<<960,  256, 0, stream>>>(h1s, 384);

    xsplit_t<<<64 * 9 * 32, 256, 0, stream>>>(x, x1s);

    // ---- TCN1: x1s -> h1s (d=1, conv residual), TILE=128, 8-wave blocks
    conv_mfma<0, 0, 1, 9, 4, 576, 384, 128><<<dim3(16, 64), 512, 0, stream>>>(
        x1s, t1_b3, t1_b5, t1_b7, t1_g, t1_bb, t1_m, t1_v,
        t1_rb, nullptr, nullptr, nullptr, nullptr, h1s, nullptr);

    padzero<<<960, 256, 0, stream>>>(h2s, 384);   // x1s dead; carve h2s pads

    // ---- TCN2: h1s -> h2s (d=2, identity residual), TILE=256
    conv_mfma<1, 1, 2, 6, 8, 384, 384, 256><<<dim3(8, 64), 512, 0, stream>>>(
        h1s, t2_b3, t2_b5, t2_b7, t2_g, t2_bb, t2_m, t2_v,
        nullptr, nullptr, nullptr, nullptr, nullptr, h2s, nullptr);

    // ---- TCN3: h2s -> h3 fp32 (d=4, identity residual + snn-BN fold), TILE=256
    conv_mfma<2, 2, 4, 6, 12, 384, 384, 256><<<dim3(8, 64), 512, 0, stream>>>(
        h2s, t3_b3, t3_b5, t3_b7, t3_g, t3_bb, t3_m, t3_v,
        nullptr, snn_g, snn_bb, snn_m, snn_v, nullptr, h3);

    // ---- SNN scan + attention pooling + classifier
    snn_head<<<dim3(Bn), dim3(192), 0, stream>>>(h3, plifw, attnw, attnb,
        c1_w, c1_b, c1_g, c1_bb, c1_m, c1_v,
        c2_w, c2_b, c2_g, c2_bb, c2_m, c2_v, c3_w, c3_b, out);
}